// Round 2
// baseline (373.721 us; speedup 1.0000x reference)
//
#include <hip/hip_runtime.h>

#define IMG    224
#define NPIX   (IMG * IMG)       // 50176
#define NELEM  (NPIX * 3)        // 150528
#define KSEL   12544             // 0.25 * IMG * IMG
#define NBINS  4096
#define MAXCAND 2048
#define NMASKW (NPIX / 32)       // 1568 words
#define NVEC   (NELEM / 4)       // 37632 float4 per sample
#define BLOCK  1024
#define NWAVE  (BLOCK / 64)      // 16

typedef float f4 __attribute__((ext_vector_type(4)));

__global__ __launch_bounds__(BLOCK) void masked_model_kernel(
    const float* __restrict__ data,
    const float* __restrict__ grad,
    float* __restrict__ out)
{
    const int b    = blockIdx.x;
    const int tid  = threadIdx.x;
    const int lane = tid & 63;
    const int wid  = tid >> 6;

    const float* g = grad + (size_t)b * NELEM;
    const float* d = data + (size_t)b * NELEM;
    float*       o = out  + (size_t)b * NELEM;

    __shared__ unsigned int hist[NBINS];
    __shared__ unsigned int mask[NMASKW];
    __shared__ unsigned int candkey[MAXCAND];
    __shared__ unsigned int candidx[MAXCAND];
    __shared__ unsigned int wtot[NWAVE];
    __shared__ unsigned int candcnt;
    __shared__ int sB1;
    __shared__ unsigned int sR;

    // ---- init LDS ----
    for (int i = tid; i < NBINS; i += BLOCK) hist[i] = 0u;
    for (int i = tid; i < NMASKW; i += BLOCK) mask[i] = 0u;
    if (tid == 0) candcnt = 0u;
    __syncthreads();

    const f4* g4 = (const f4*)g;

    // ---- pass 1: 4096-bin histogram, 4x unrolled loads for MLP ----
    {
        int i = tid;
        for (; i + 3 * BLOCK < NVEC; i += 4 * BLOCK) {
            f4 v0 = g4[i];
            f4 v1 = g4[i + BLOCK];
            f4 v2 = g4[i + 2 * BLOCK];
            f4 v3 = g4[i + 3 * BLOCK];
            #pragma unroll
            for (int c = 0; c < 4; ++c) atomicAdd(&hist[min((int)(v0[c] * 4096.0f), NBINS - 1)], 1u);
            #pragma unroll
            for (int c = 0; c < 4; ++c) atomicAdd(&hist[min((int)(v1[c] * 4096.0f), NBINS - 1)], 1u);
            #pragma unroll
            for (int c = 0; c < 4; ++c) atomicAdd(&hist[min((int)(v2[c] * 4096.0f), NBINS - 1)], 1u);
            #pragma unroll
            for (int c = 0; c < 4; ++c) atomicAdd(&hist[min((int)(v3[c] * 4096.0f), NBINS - 1)], 1u);
        }
        for (; i < NVEC; i += BLOCK) {
            f4 v = g4[i];
            #pragma unroll
            for (int c = 0; c < 4; ++c) atomicAdd(&hist[min((int)(v[c] * 4096.0f), NBINS - 1)], 1u);
        }
    }
    __syncthreads();

    // ---- suffix sums over 1024 groups of 4 bins: wave shuffle scan, 1 barrier ----
    {
        unsigned int s = hist[4 * tid] + hist[4 * tid + 1]
                       + hist[4 * tid + 2] + hist[4 * tid + 3];

        // inclusive suffix scan within the wave (lane 0 ends with the wave total)
        unsigned int v = s;
        #pragma unroll
        for (int off = 1; off < 64; off <<= 1) {
            unsigned int u = __shfl_down(v, off);
            if (lane + off < 64) v += u;
        }
        if (lane == 0) wtot[wid] = v;
        __syncthreads();

        // add suffix of later waves' totals (broadcast LDS reads, <=15 per thread)
        unsigned int woff = 0;
        for (int w = wid + 1; w < NWAVE; ++w) woff += wtot[w];

        unsigned int a  = v + woff;   // suffix sum starting at group tid
        unsigned int nx = a - s;      // suffix sum starting at group tid+1

        // ---- find threshold bin B1 and residual rank r within it ----
        if (a >= KSEL && nx < KSEL) {
            unsigned int cum = nx;
            for (int i = 3; i >= 0; --i) {
                unsigned int h = hist[4 * tid + i];
                cum += h;
                if (cum >= KSEL) {
                    sB1 = 4 * tid + i;
                    sR  = KSEL - (cum - h);   // how many to take from bin B1
                    break;
                }
            }
        }
    }
    __syncthreads();

    // ---- pass 2: mask bins > B1; compact bin == B1 candidates; 4x unrolled ----
    {
        const int B1 = sB1;
        auto classify = [&](float val, int idx) {
            int bin = min((int)(val * 4096.0f), NBINS - 1);
            if (bin > B1) {
                int p = idx % NPIX;
                atomicOr(&mask[p >> 5], 1u << (p & 31));
            } else if (bin == B1) {
                unsigned int c2 = atomicAdd(&candcnt, 1u);
                if (c2 < MAXCAND) {
                    candkey[c2] = __float_as_uint(val); // nonneg: uint order == float order
                    candidx[c2] = (unsigned int)idx;
                }
            }
        };
        int i = tid;
        for (; i + 3 * BLOCK < NVEC; i += 4 * BLOCK) {
            f4 v0 = g4[i];
            f4 v1 = g4[i + BLOCK];
            f4 v2 = g4[i + 2 * BLOCK];
            f4 v3 = g4[i + 3 * BLOCK];
            #pragma unroll
            for (int c = 0; c < 4; ++c) classify(v0[c], 4 * i + c);
            #pragma unroll
            for (int c = 0; c < 4; ++c) classify(v1[c], 4 * (i + BLOCK) + c);
            #pragma unroll
            for (int c = 0; c < 4; ++c) classify(v2[c], 4 * (i + 2 * BLOCK) + c);
            #pragma unroll
            for (int c = 0; c < 4; ++c) classify(v3[c], 4 * (i + 3 * BLOCK) + c);
        }
        for (; i < NVEC; i += BLOCK) {
            f4 v = g4[i];
            #pragma unroll
            for (int c = 0; c < 4; ++c) classify(v[c], 4 * i + c);
        }
    }
    __syncthreads();

    // ---- exact rank among candidates: (value desc, index asc) = top_k order ----
    {
        unsigned int n = candcnt < MAXCAND ? candcnt : MAXCAND;
        unsigned int r = sR;
        for (unsigned int j = tid; j < n; j += BLOCK) {
            unsigned int kj = candkey[j];
            unsigned int ij = candidx[j];
            unsigned int rank = 0;
            for (unsigned int i = 0; i < n; ++i) {
                unsigned int ki = candkey[i];
                rank += (ki > kj) || (ki == kj && candidx[i] < ij);
            }
            if (rank < r) {
                int p = (int)(ij % NPIX);
                atomicOr(&mask[p >> 5], 1u << (p & 31));
            }
        }
    }
    __syncthreads();

    // ---- output: masked copy of data; nt loads/stores (touched once), 4x unrolled ----
    {
        const f4* d4 = (const f4*)d;
        f4*       o4 = (f4*)o;
        auto apply = [&](f4 v, int i) -> f4 {
            int e = 4 * i;
            int p0 = e / 3, p1 = (e + 1) / 3, p2 = (e + 2) / 3, p3 = (e + 3) / 3;
            if ((mask[p0 >> 5] >> (p0 & 31)) & 1u) v.x = 0.0f;
            if ((mask[p1 >> 5] >> (p1 & 31)) & 1u) v.y = 0.0f;
            if ((mask[p2 >> 5] >> (p2 & 31)) & 1u) v.z = 0.0f;
            if ((mask[p3 >> 5] >> (p3 & 31)) & 1u) v.w = 0.0f;
            return v;
        };
        int i = tid;
        for (; i + 3 * BLOCK < NVEC; i += 4 * BLOCK) {
            f4 v0 = __builtin_nontemporal_load(&d4[i]);
            f4 v1 = __builtin_nontemporal_load(&d4[i + BLOCK]);
            f4 v2 = __builtin_nontemporal_load(&d4[i + 2 * BLOCK]);
            f4 v3 = __builtin_nontemporal_load(&d4[i + 3 * BLOCK]);
            __builtin_nontemporal_store(apply(v0, i),             &o4[i]);
            __builtin_nontemporal_store(apply(v1, i + BLOCK),     &o4[i + BLOCK]);
            __builtin_nontemporal_store(apply(v2, i + 2 * BLOCK), &o4[i + 2 * BLOCK]);
            __builtin_nontemporal_store(apply(v3, i + 3 * BLOCK), &o4[i + 3 * BLOCK]);
        }
        for (; i < NVEC; i += BLOCK) {
            f4 v = d4[i];
            o4[i] = apply(v, i);
        }
    }
}

extern "C" void kernel_launch(void* const* d_in, const int* in_sizes, int n_in,
                              void* d_out, int out_size, void* d_ws, size_t ws_size,
                              hipStream_t stream) {
    const float* data = (const float*)d_in[0];   // [256, 224, 224, 3] fp32
    const float* grad = (const float*)d_in[1];   // [256, 150528] fp32
    float* out = (float*)d_out;                  // [256, 224, 224, 3] fp32

    const int B = in_sizes[0] / NELEM;           // 256
    masked_model_kernel<<<B, BLOCK, 0, stream>>>(data, grad, out);
}